// Round 7
// baseline (157.049 us; speedup 1.0000x reference)
//
#include <hip/hip_runtime.h>
#include <hip/hip_bf16.h>
#include <math.h>

#define BATCH 4096
#define XD    784
#define HDIM  512
#define ZD    16
#define NS    8
#define ZS    128
#define NSAMP (BATCH * NS)   // 32768
#define STDN  (ZD * NS * NS) // 1024
#define KP1   800            // K of enc1, padded 784->800
#define NMS   1152           // 128 (mu) + 1024 (std1)
#define NP2   800            // w2t rows padded 784->800 (5*160)

typedef __attribute__((ext_vector_type(8))) short bf16x8;
typedef __attribute__((ext_vector_type(4))) float f32x4;

__device__ inline unsigned short f2bf(float f) {
    unsigned int u = __float_as_uint(f);
    unsigned int r = (u + 0x7fffu + ((u >> 16) & 1u)) >> 16;
    return (unsigned short)r;
}

// HBM -> LDS direct 16B async copy (global_load_lds_dwordx4).
// LDS semantics: wave-uniform base + lane*16; our per-lane lds ptr IS
// base + lane*16 (linear layout), so passing it is correct.
__device__ __forceinline__ void gload16(const unsigned short* g, unsigned short* l) {
    __builtin_amdgcn_global_load_lds(
        (const __attribute__((address_space(1))) unsigned int*)g,
        (__attribute__((address_space(3))) unsigned int*)l,
        16, 0, 0);
}

// ---------------------------------------------------------------------------
// Merged prep (unchanged from R6): block ranges
//   [0,1600)    : W1^T   -> w1t [512][800]
//   [1600,3200) : xpad   -> x_bf [4096][800]
//   [3200,5504) : [Wmu|Wstd]^T -> wmst [1152][512]
//   [5504,7104) : Wd2^T  -> w2tp [800][512] (rows>=784 zero)
// ---------------------------------------------------------------------------
__global__ __launch_bounds__(256)
void prep_kernel(const float* __restrict__ W1, const float* __restrict__ x,
                 const float* __restrict__ Wmu, const float* __restrict__ Wstd,
                 const float* __restrict__ Wd2,
                 unsigned short* __restrict__ w1t, unsigned short* __restrict__ x_bf,
                 unsigned short* __restrict__ wmst, unsigned short* __restrict__ w2tp)
{
    __shared__ unsigned short t[16][17];
    const int tid = threadIdx.x;
    const int tx = tid & 15, ty = tid >> 4;
    const int bid = blockIdx.x;

    if (bid < 1600) {                      // W1^T (K=784 -> 800, N=512)
        const int bx = bid & 31, by = bid >> 5;        // 32 x 50
        const int n = bx * 16 + tx, k = by * 16 + ty;
        t[ty][tx] = (k < XD) ? f2bf(W1[(size_t)k * HDIM + n]) : (unsigned short)0;
        __syncthreads();
        w1t[(size_t)(bx * 16 + ty) * KP1 + (by * 16 + tx)] = t[tx][ty];
    } else if (bid < 3200) {               // xpad
        const int idx = (bid - 1600) * 256 + tid;
        const int row = idx / 100;
        const int c8 = idx - row * 100;
        const int k0 = c8 * 8;
        ushort4 o0 = {0, 0, 0, 0}, o1 = {0, 0, 0, 0};
        if (k0 < XD) {
            const float4 a = *reinterpret_cast<const float4*>(&x[(size_t)row * XD + k0]);
            const float4 b = *reinterpret_cast<const float4*>(&x[(size_t)row * XD + k0 + 4]);
            o0.x = f2bf(a.x); o0.y = f2bf(a.y); o0.z = f2bf(a.z); o0.w = f2bf(a.w);
            o1.x = f2bf(b.x); o1.y = f2bf(b.y); o1.z = f2bf(b.z); o1.w = f2bf(b.w);
        }
        *reinterpret_cast<ushort4*>(&x_bf[(size_t)row * KP1 + k0]) = o0;
        *reinterpret_cast<ushort4*>(&x_bf[(size_t)row * KP1 + k0 + 4]) = o1;
    } else if (bid < 5504) {               // [Wmu|Wstd]^T (N=1152, K=512)
        const int b = bid - 3200;                      // 72 x 32
        const int bx = b % 72, by = b / 72;
        const int n = bx * 16 + tx, k = by * 16 + ty;
        const float v = (n < ZS) ? Wmu[(size_t)k * ZS + n]
                                 : Wstd[(size_t)k * STDN + (n - ZS)];
        t[ty][tx] = f2bf(v);
        __syncthreads();
        wmst[(size_t)(bx * 16 + ty) * HDIM + (by * 16 + tx)] = t[tx][ty];
    } else {                               // Wd2^T (N=784 -> 800 rows, K=512)
        const int b = bid - 5504;                      // 50 x 32
        const int bx = b % 50, by = b / 50;
        const int n = bx * 16 + tx, k = by * 16 + ty;
        t[ty][tx] = (n < XD) ? f2bf(Wd2[(size_t)k * XD + n]) : (unsigned short)0;
        __syncthreads();
        w2tp[(size_t)(bx * 16 + ty) * HDIM + (by * 16 + tx)] = t[tx][ty];
    }
}

// ---------------------------------------------------------------------------
// Encoder MFMA GEMM, global_load_lds staging, linear LDS [128][32] bf16.
// out = [relu](A @ Bt^T + bias). BM=BN=128, BK=32, 4 waves.
// ---------------------------------------------------------------------------
template<int OUT_BF16>
__global__ __launch_bounds__(256)
void enc_mfma(const unsigned short* __restrict__ A,
              const unsigned short* __restrict__ Bt,
              const float* __restrict__ bias0, const float* __restrict__ bias1,
              int bsplit, void* __restrict__ Cout, int ldc, int K)
{
    __shared__ __align__(16) unsigned short Al[2][128 * 32];
    __shared__ __align__(16) unsigned short Bl[2][128 * 32];

    const int tid = threadIdx.x;
    const int m0 = blockIdx.x * 128;
    const int n0 = blockIdx.y * 128;
    const int wave = tid >> 6;
    const int lane = tid & 63;
    const int lr = lane & 15;
    const int kg = lane >> 4;
    const int nkt = K >> 5;

    const int rS = tid >> 2;               // staging row 0..63
    const int cS = (tid & 3) * 8;          // staging k-chunk (elements)

    f32x4 acc[2][8];
    #pragma unroll
    for (int i = 0; i < 2; ++i)
        #pragma unroll
        for (int j = 0; j < 8; ++j)
            acc[i][j] = (f32x4){0.f, 0.f, 0.f, 0.f};

    // stage k-tile kt into buffer b (4 KB per issue-pair, linear LDS)
    #define ENC_STAGE(b, kt)                                                          \
    {                                                                                 \
        const int k0 = (kt) * 32 + cS;                                                \
        gload16(&A[(size_t)(m0 + rS) * K + k0],       &Al[b][(size_t)tid * 8]);       \
        gload16(&A[(size_t)(m0 + rS + 64) * K + k0],  &Al[b][(size_t)(tid + 256) * 8]);\
        gload16(&Bt[(size_t)(n0 + rS) * K + k0],      &Bl[b][(size_t)tid * 8]);       \
        gload16(&Bt[(size_t)(n0 + rS + 64) * K + k0], &Bl[b][(size_t)(tid + 256) * 8]);\
    }

    ENC_STAGE(0, 0);
    __syncthreads();

    int buf = 0;
    for (int kt = 0; kt < nkt; ++kt) {
        if (kt + 1 < nkt) ENC_STAGE(buf ^ 1, kt + 1);

        bf16x8 af[2], bfr[8];
        #pragma unroll
        for (int mi = 0; mi < 2; ++mi)
            af[mi] = *reinterpret_cast<const bf16x8*>(
                &Al[buf][(wave * 32 + mi * 16 + lr) * 32 + kg * 8]);
        #pragma unroll
        for (int nf = 0; nf < 8; ++nf)
            bfr[nf] = *reinterpret_cast<const bf16x8*>(
                &Bl[buf][(nf * 16 + lr) * 32 + kg * 8]);
        #pragma unroll
        for (int mi = 0; mi < 2; ++mi)
            #pragma unroll
            for (int nf = 0; nf < 8; ++nf)
                acc[mi][nf] = __builtin_amdgcn_mfma_f32_16x16x32_bf16(af[mi], bfr[nf], acc[mi][nf], 0, 0, 0);

        __syncthreads();   // drains global_load_lds (vmcnt) + LDS reads
        buf ^= 1;
    }

    const int mrow = m0 + wave * 32;
    #pragma unroll
    for (int nf = 0; nf < 8; ++nf) {
        const int col = n0 + nf * 16 + lr;
        const float bb = (col < bsplit) ? bias0[col] : bias1[col - bsplit];
        #pragma unroll
        for (int mi = 0; mi < 2; ++mi) {
            #pragma unroll
            for (int j = 0; j < 4; ++j) {
                const int row = mrow + mi * 16 + kg * 4 + j;
                const float v = acc[mi][nf][j] + bb;
                if (OUT_BF16)
                    ((unsigned short*)Cout)[(size_t)row * ldc + col] = f2bf(fmaxf(v, 0.f));
                else
                    ((float*)Cout)[(size_t)row * ldc + col] = v;
            }
        }
    }
    #undef ENC_STAGE
}

// ---------------------------------------------------------------------------
// Sparse sample (unchanged).
// ---------------------------------------------------------------------------
__global__ __launch_bounds__(256)
void sample_kernel(const float* __restrict__ ms, const float* __restrict__ eps,
                   float* __restrict__ mu_out,
                   float* __restrict__ z_out, float* __restrict__ logvar_out)
{
    const int idx = blockIdx.x * 256 + threadIdx.x;
    const int b = idx >> 7;
    const int r = idx & 127;
    const int d = r & 15;
    const int s1 = r >> 4;

    const float* v = &ms[(size_t)b * NMS + ZS + r * NS];
    const float* e = &eps[(size_t)b * ZS + d];
    float zacc = 0.f, dacc = 0.f;
    #pragma unroll
    for (int k = 0; k < NS; ++k) {
        const float vv = v[k];
        zacc += vv * e[16 * k];
        dacc += vv * vv;
    }
    const float muv = ms[(size_t)b * NMS + r];
    mu_out[(size_t)b * ZS + r] = muv;
    const float zv = muv + zacc;
    const size_t orow = (size_t)(b * NS + s1) * ZD + d;
    z_out[orow] = zv;
    logvar_out[orow] = logf(dacc);
}

// ---------------------------------------------------------------------------
// hd = relu(z @ Wd1 + bd1) in bf16 (unchanged).
// ---------------------------------------------------------------------------
__global__ __launch_bounds__(256)
void hd_kernel(const float* __restrict__ z, const float* __restrict__ Wd1,
               const float* __restrict__ bd1, unsigned short* __restrict__ hd)
{
    const int idx = blockIdx.x * 256 + threadIdx.x;
    const int m = idx >> 7;
    const int n0 = (idx & 127) * 4;
    const float* zr = &z[(size_t)m * ZD];
    float4 a = *reinterpret_cast<const float4*>(&bd1[n0]);
    #pragma unroll
    for (int k = 0; k < ZD; ++k) {
        const float zk = zr[k];
        float4 w = *reinterpret_cast<const float4*>(&Wd1[(size_t)k * HDIM + n0]);
        a.x += zk * w.x; a.y += zk * w.y; a.z += zk * w.z; a.w += zk * w.w;
    }
    ushort4 o;
    o.x = f2bf(fmaxf(a.x, 0.f));
    o.y = f2bf(fmaxf(a.y, 0.f));
    o.z = f2bf(fmaxf(a.z, 0.f));
    o.w = f2bf(fmaxf(a.w, 0.f));
    *reinterpret_cast<ushort4*>(&hd[(size_t)m * HDIM + n0]) = o;
}

// ---------------------------------------------------------------------------
// Decoder GEMM, global_load_lds staging, linear LDS. recon = sigmoid(hd@Wd2+bd2)
// M=32768, N=784(->800), K=512. BM=128, BN=160, BK=32, 4 waves as 2x2
// (each 64x80, acc[4][5]). LDS 36 KB -> 4 blocks/CU.
// ---------------------------------------------------------------------------
#define DBM 128
#define DBN 160
#define DNKT 16

__global__ __launch_bounds__(256)
void decoder_mfma(const unsigned short* __restrict__ hd,
                  const unsigned short* __restrict__ w2tp,
                  const float* __restrict__ bd2,
                  float* __restrict__ recon)
{
    __shared__ __align__(16) unsigned short Al[2][DBM * 32];   // 8 KB each
    __shared__ __align__(16) unsigned short Bl[2][DBN * 32];   // 10 KB each

    const int tid = threadIdx.x;
    const int m0 = blockIdx.x * DBM;
    const int n0 = blockIdx.y * DBN;
    const int wave = tid >> 6;
    const int wr = wave >> 1;
    const int wc = wave & 1;
    const int lane = tid & 63;
    const int lr = lane & 15;
    const int kg = lane >> 4;

    const int rS = tid >> 2;               // staging row 0..63
    const int cS = (tid & 3) * 8;          // staging k-chunk (elements)

    f32x4 acc[4][5];
    #pragma unroll
    for (int i = 0; i < 4; ++i)
        #pragma unroll
        for (int j = 0; j < 5; ++j)
            acc[i][j] = (f32x4){0.f, 0.f, 0.f, 0.f};

    // stage k-tile kt into buffer b: A 8KB (2 issues), B 10KB (2.5 issues)
    #define DEC_STAGE(b, kt)                                                             \
    {                                                                                    \
        const int k0 = (kt) * 32 + cS;                                                   \
        gload16(&hd[(size_t)(m0 + rS) * HDIM + k0],         &Al[b][(size_t)tid * 8]);    \
        gload16(&hd[(size_t)(m0 + rS + 64) * HDIM + k0],    &Al[b][(size_t)(tid + 256) * 8]); \
        gload16(&w2tp[(size_t)(n0 + rS) * HDIM + k0],       &Bl[b][(size_t)tid * 8]);    \
        gload16(&w2tp[(size_t)(n0 + rS + 64) * HDIM + k0],  &Bl[b][(size_t)(tid + 256) * 8]); \
        if (tid < 128)                                                                   \
            gload16(&w2tp[(size_t)(n0 + rS + 128) * HDIM + k0], &Bl[b][(size_t)(tid + 512) * 8]); \
    }

    DEC_STAGE(0, 0);
    __syncthreads();

    int buf = 0;
    for (int kt = 0; kt < DNKT; ++kt) {
        if (kt + 1 < DNKT) DEC_STAGE(buf ^ 1, kt + 1);

        bf16x8 af[4], bfr[5];
        #pragma unroll
        for (int mi = 0; mi < 4; ++mi)
            af[mi] = *reinterpret_cast<const bf16x8*>(
                &Al[buf][(wr * 64 + mi * 16 + lr) * 32 + kg * 8]);
        #pragma unroll
        for (int nf = 0; nf < 5; ++nf)
            bfr[nf] = *reinterpret_cast<const bf16x8*>(
                &Bl[buf][(wc * 80 + nf * 16 + lr) * 32 + kg * 8]);
        #pragma unroll
        for (int mi = 0; mi < 4; ++mi)
            #pragma unroll
            for (int nf = 0; nf < 5; ++nf)
                acc[mi][nf] = __builtin_amdgcn_mfma_f32_16x16x32_bf16(af[mi], bfr[nf], acc[mi][nf], 0, 0, 0);

        __syncthreads();
        buf ^= 1;
    }

    // epilogue: bias + sigmoid, guarded f32 store
    const int mrow = m0 + wr * 64;
    #pragma unroll
    for (int nf = 0; nf < 5; ++nf) {
        const int col = n0 + wc * 80 + nf * 16 + lr;
        if (col < XD) {
            const float bias = bd2[col];
            #pragma unroll
            for (int mi = 0; mi < 4; ++mi) {
                #pragma unroll
                for (int j = 0; j < 4; ++j) {
                    const int row = mrow + mi * 16 + kg * 4 + j;
                    const float v = acc[mi][nf][j] + bias;
                    recon[(size_t)row * XD + col] = 1.f / (1.f + __expf(-v));
                }
            }
        }
    }
    #undef DEC_STAGE
}

// ---------------------------------------------------------------------------
extern "C" void kernel_launch(void* const* d_in, const int* in_sizes, int n_in,
                              void* d_out, int out_size, void* d_ws, size_t ws_size,
                              hipStream_t stream)
{
    const float* x    = (const float*)d_in[0];
    const float* eps  = (const float*)d_in[1];
    const float* W1   = (const float*)d_in[2];
    const float* b1   = (const float*)d_in[3];
    const float* Wmu  = (const float*)d_in[4];
    const float* bmu  = (const float*)d_in[5];
    const float* Wstd = (const float*)d_in[6];
    const float* bstd = (const float*)d_in[7];
    const float* Wd1  = (const float*)d_in[8];
    const float* bd1  = (const float*)d_in[9];
    const float* Wd2  = (const float*)d_in[10];
    const float* bd2  = (const float*)d_in[11];

    float* out    = (float*)d_out;
    float* recon  = out;
    float* mu     = recon + (size_t)NSAMP * XD;
    float* logvar = mu + (size_t)BATCH * ZS;
    float* zout   = logvar + (size_t)NSAMP * ZD;

    char* wsb = (char*)d_ws;
    unsigned short* hd   = (unsigned short*)wsb;                            // 32 MiB
    unsigned short* x_bf = (unsigned short*)wsb;                            // 6.25 MiB
    unsigned short* h    = (unsigned short*)(wsb + (size_t)68 * 1048576 / 10);
    float*          ms   = (float*)(wsb + (size_t)11 * 1048576);
    unsigned short* w1t  = (unsigned short*)(wsb + (size_t)295 * 1048576 / 10);
    unsigned short* wmst = (unsigned short*)(wsb + (size_t)305 * 1048576 / 10);
    unsigned short* w2tp = (unsigned short*)(wsb + (size_t)32 * 1048576);   // 800x512 bf16

    prep_kernel<<<7104, 256, 0, stream>>>(W1, x, Wmu, Wstd, Wd2, w1t, x_bf, wmst, w2tp);

    enc_mfma<1><<<dim3(BATCH / 128, HDIM / 128), 256, 0, stream>>>(
        x_bf, w1t, b1, b1, HDIM, h, HDIM, KP1);
    enc_mfma<0><<<dim3(BATCH / 128, NMS / 128), 256, 0, stream>>>(
        h, wmst, bmu, bstd, ZS, ms, NMS, HDIM);

    sample_kernel<<<(BATCH * ZS) / 256, 256, 0, stream>>>(ms, eps, mu, zout, logvar);

    hd_kernel<<<(NSAMP * 128) / 256, 256, 0, stream>>>(zout, Wd1, bd1, hd);
    decoder_mfma<<<dim3(NSAMP / DBM, NP2 / DBN), 256, 0, stream>>>(hd, w2tp, bd2, recon);
}